// Round 14
// baseline (223.621 us; speedup 1.0000x reference)
//
#include <hip/hip_runtime.h>
#include <hip/hip_fp16.h>

#define HDIM 64
#define INDIM 128
#define OUTDIM 32
#define CAP 64        // padded-CSR capacity per node; deg ~ Poisson(16)
#define BNODES 128    // nodes per bucket (bucket = dst >> 7)
#define EPB 4096      // edges per block in pass A
#define BCAP 2304     // per-bucket edge capacity (mean 2046, +5.7 sigma)
#define SRCBITS 17    // src ids < 2^17 (n <= 131072)

// ---------------- pass A: bin edges by dst-bucket ----------------
__global__ __launch_bounds__(256) void bin_edges(const int* __restrict__ dst,
                                                 const int* __restrict__ src,
                                                 int* __restrict__ gcur,
                                                 int* __restrict__ binned,
                                                 int e, int nb) {
    __shared__ int hist[1024];
    __shared__ int base[1024];
    for (int i = threadIdx.x; i < nb; i += 256) hist[i] = 0;
    __syncthreads();

    int e0 = blockIdx.x * EPB + (int)threadIdx.x * 16;
    int d[16], s[16], p[16];
    bool vec_ok = ((e & 3) == 0);
    #pragma unroll
    for (int k = 0; k < 4; k++) {
        int i = e0 + 4 * k;
        if (vec_ok && i + 4 <= e) {
            int4 d4 = *(const int4*)(dst + i);
            int4 s4 = *(const int4*)(src + i);
            d[4*k+0] = d4.x; d[4*k+1] = d4.y; d[4*k+2] = d4.z; d[4*k+3] = d4.w;
            s[4*k+0] = s4.x; s[4*k+1] = s4.y; s[4*k+2] = s4.z; s[4*k+3] = s4.w;
        } else {
            #pragma unroll
            for (int j = 0; j < 4; j++) {
                int ii = i + j;
                if (ii < e) { d[4*k+j] = dst[ii]; s[4*k+j] = src[ii]; }
                else        { d[4*k+j] = -1;      s[4*k+j] = 0; }
            }
        }
    }
    #pragma unroll
    for (int k = 0; k < 16; k++)
        if (d[k] >= 0) p[k] = atomicAdd(&hist[d[k] >> 7], 1);
    __syncthreads();
    for (int b = threadIdx.x; b < nb; b += 256) {
        int h = hist[b];
        base[b] = h ? atomicAdd(&gcur[b], h) : 0;
    }
    __syncthreads();
    #pragma unroll
    for (int k = 0; k < 16; k++) {
        if (d[k] < 0) continue;
        int b = d[k] >> 7;
        int pos = base[b] + p[k];
        if (pos < BCAP)
            binned[(size_t)b * BCAP + pos] = ((d[k] & (BNODES - 1)) << SRCBITS) | s[k];
    }
}

// ---------------- pass B: per-bucket padded CSR built in LDS ----------------
__global__ __launch_bounds__(256) void build_csr(const int* __restrict__ gcur,
                                                 const int* __restrict__ binned,
                                                 int* __restrict__ cnt,
                                                 float* __restrict__ rs,
                                                 int* __restrict__ csr, int n) {
    __shared__ int lcsr[BNODES * CAP];   // 32 KiB
    __shared__ int lcnt[BNODES];
    if (threadIdx.x < BNODES) lcnt[threadIdx.x] = 0;
    __syncthreads();
    int b = blockIdx.x;
    int m = min(gcur[b], BCAP);
    const int* be = binned + (size_t)b * BCAP;
    for (int i = threadIdx.x; i < m; i += 256) {
        int v = be[i];
        int ld = v >> SRCBITS;
        int pos = atomicAdd(&lcnt[ld], 1);
        if (pos < CAP) lcsr[ld * CAP + pos] = v & ((1 << SRCBITS) - 1);
    }
    __syncthreads();
    int4* gout = (int4*)(csr + (size_t)b * (BNODES * CAP));
    const int4* lin = (const int4*)lcsr;
    #pragma unroll 2
    for (int i = threadIdx.x; i < BNODES * CAP / 4; i += 256) gout[i] = lin[i];
    int node = b * BNODES + (int)threadIdx.x;
    if (threadIdx.x < BNODES && node < n) {
        int c = lcnt[threadIdx.x];
        cnt[node] = c;
        rs[node] = rsqrtf((float)c + 1.0f);
    }
}

// ---------------- input GEMM: h = x @ W_in (+ rs-scaled fp16 shadow) -------
// R=2; no launch-bounds min-arg (R10: hipcc CUDA semantics -> VGPR=32 spill).
// BM=64/BLOCK=256 -> 1563 blocks (~6/CU) for load balance.
template<int K, int N, int BM, int BLOCK, bool RELU, bool EMIT16>
__global__ __launch_bounds__(BLOCK) void gemm_node(const float* __restrict__ A,
                                                   const float* __restrict__ W,
                                                   float* __restrict__ C,
                                                   __half* __restrict__ C16,
                                                   const float* __restrict__ rs,
                                                   int n) {
    constexpr int TX = N / 8;
    constexpr int TY = BLOCK / TX;
    constexpr int R = BM / TY;
    static_assert(BM % TY == 0, "");
    __shared__ float w[K * N];
    for (int i = threadIdx.x; i < K * N; i += BLOCK) w[i] = W[i];
    __syncthreads();
    int tx = (int)threadIdx.x % TX;
    int ty = (int)threadIdx.x / TX;
    int base = blockIdx.x * BM + ty * R;

    const float* pa[R];
    #pragma unroll
    for (int r = 0; r < R; r++) {
        int row = base + r;
        row = row < n ? row : n - 1;      // clamp: loads always safe
        pa[r] = A + (size_t)row * K;
    }

    float acc[R][8];
    #pragma unroll
    for (int r = 0; r < R; r++)
        #pragma unroll
        for (int i = 0; i < 8; i++) acc[r][i] = 0.f;

    #pragma unroll 2
    for (int k = 0; k < K; k += 4) {
        float4 a4[R];
        #pragma unroll
        for (int r = 0; r < R; r++) a4[r] = *(const float4*)(pa[r] + k);
        #pragma unroll
        for (int kk = 0; kk < 4; kk++) {
            float4 b0 = *(const float4*)(w + (k + kk) * N + tx * 8);
            float4 b1 = *(const float4*)(w + (k + kk) * N + tx * 8 + 4);
            #pragma unroll
            for (int r = 0; r < R; r++) {
                float av = (kk == 0) ? a4[r].x : (kk == 1) ? a4[r].y
                         : (kk == 2) ? a4[r].z : a4[r].w;
                acc[r][0] += av * b0.x; acc[r][1] += av * b0.y;
                acc[r][2] += av * b0.z; acc[r][3] += av * b0.w;
                acc[r][4] += av * b1.x; acc[r][5] += av * b1.y;
                acc[r][6] += av * b1.z; acc[r][7] += av * b1.w;
            }
        }
    }

    #pragma unroll
    for (int r = 0; r < R; r++) {
        int node = base + r;
        if (node >= n) continue;
        float4 o0, o1;
        o0.x = RELU ? fmaxf(acc[r][0], 0.f) : acc[r][0];
        o0.y = RELU ? fmaxf(acc[r][1], 0.f) : acc[r][1];
        o0.z = RELU ? fmaxf(acc[r][2], 0.f) : acc[r][2];
        o0.w = RELU ? fmaxf(acc[r][3], 0.f) : acc[r][3];
        o1.x = RELU ? fmaxf(acc[r][4], 0.f) : acc[r][4];
        o1.y = RELU ? fmaxf(acc[r][5], 0.f) : acc[r][5];
        o1.z = RELU ? fmaxf(acc[r][6], 0.f) : acc[r][6];
        o1.w = RELU ? fmaxf(acc[r][7], 0.f) : acc[r][7];
        *(float4*)(C + (size_t)node * N + tx * 8) = o0;
        *(float4*)(C + (size_t)node * N + tx * 8 + 4) = o1;
        if (EMIT16) {
            float rsv = rs[node];
            __half2 p0 = __floats2half2_rn(rsv * o0.x, rsv * o0.y);
            __half2 p1 = __floats2half2_rn(rsv * o0.z, rsv * o0.w);
            __half2 p2 = __floats2half2_rn(rsv * o1.x, rsv * o1.y);
            __half2 p3 = __floats2half2_rn(rsv * o1.z, rsv * o1.w);
            uint4 pk;
            pk.x = *(unsigned int*)&p0;
            pk.y = *(unsigned int*)&p1;
            pk.z = *(unsigned int*)&p2;
            pk.w = *(unsigned int*)&p3;
            *(uint4*)(C16 + (size_t)node * N + tx * 8) = pk;
        }
    }
}

// ---------------- fused GCN layer: gather + skip + GEMM (+ Wout if LAST) ---
// Wave-pipelined: each wave owns 8 nodes — gathers them into its PRIVATE LDS
// slice hbuf[wave] (stride 68: all access patterns <=2-way bank aliased),
// then GEMMs those rows (W in the proven gemm_node LDS layout, 0 conflicts
// measured R8-R13). No __syncthreads between phases: DS ops of a wave are
// in-order and slices are wave-private, so waves pipeline (one wave's gather
// stalls overlap other waves' GEMM VALU). Deletes the agg global round-trip.
// LDS: 33.4KB (4 blk/CU, 100% waves) / LAST 41.4KB (3 blk/CU, 75%).
template<int LAST>
__global__ __launch_bounds__(512) void layer_fused2(
    const __half* __restrict__ h16in, float* __restrict__ h,
    __half* __restrict__ h16out, float* __restrict__ outp,
    const float* __restrict__ Wlayer, const float* __restrict__ Wout,
    const int* __restrict__ cnt, const int* __restrict__ csr,
    const float* __restrict__ rs, int n)
{
    __shared__ float w[HDIM * HDIM];                        // 16 KB
    __shared__ float wo[LAST ? HDIM * OUTDIM : 4];          // 8 KB if LAST
    __shared__ __align__(16) float hbuf[8][8][68];          // 17.4 KB

    for (int i = threadIdx.x; i < HDIM * HDIM; i += 512) w[i] = Wlayer[i];
    if (LAST)
        for (int i = threadIdx.x; i < HDIM * OUTDIM; i += 512) wo[i] = Wout[i];
    __syncthreads();

    int wave = threadIdx.x >> 6, lane = threadIdx.x & 63;
    int grp = lane >> 4, gl = lane & 15;
    int wbase = blockIdx.x * 64 + wave * 8;

    // ---- phase 1: gather 8 nodes into hbuf[wave] (with rs scale + skip) ----
    for (int i = 0; i < 8; i++) {
        int node = wbase + i;
        if (node >= n) break;                 // wave-uniform
        int c = min(cnt[node], CAP);
        int sl = 0;
        if (lane < c) sl = csr[node * CAP + lane];
        float4 acc0 = make_float4(0.f, 0.f, 0.f, 0.f);
        float4 acc1 = make_float4(0.f, 0.f, 0.f, 0.f);
        int trips = (c + 3) >> 2;
        int j = 0;
        for (; j + 2 <= trips; j += 2) {
            int t0 = 4 * j + grp, t1 = t0 + 4;
            float w0 = (t0 < c) ? 1.f : 0.f;
            float w1 = (t1 < c) ? 1.f : 0.f;
            int u0 = min(t0, c - 1);
            int u1 = min(t1, c - 1);
            int s0 = __shfl(sl, u0);
            int s1 = __shfl(sl, u1);
            uint2 q0 = ((const uint2*)(h16in + (size_t)s0 * HDIM))[gl];
            uint2 q1 = ((const uint2*)(h16in + (size_t)s1 * HDIM))[gl];
            float2 f0a = __half22float2(*(__half2*)&q0.x);
            float2 f0b = __half22float2(*(__half2*)&q0.y);
            float2 f1a = __half22float2(*(__half2*)&q1.x);
            float2 f1b = __half22float2(*(__half2*)&q1.y);
            acc0.x += w0 * f0a.x; acc0.y += w0 * f0a.y;
            acc0.z += w0 * f0b.x; acc0.w += w0 * f0b.y;
            acc1.x += w1 * f1a.x; acc1.y += w1 * f1a.y;
            acc1.z += w1 * f1b.x; acc1.w += w1 * f1b.y;
        }
        if (j < trips) {
            int t = 4 * j + grp;
            float wv = (t < c) ? 1.f : 0.f;
            int u = min(t, c - 1);
            int s = __shfl(sl, u);
            uint2 q = ((const uint2*)(h16in + (size_t)s * HDIM))[gl];
            float2 fa = __half22float2(*(__half2*)&q.x);
            float2 fb = __half22float2(*(__half2*)&q.y);
            acc0.x += wv * fa.x; acc0.y += wv * fa.y;
            acc0.z += wv * fb.x; acc0.w += wv * fb.y;
        }
        acc0.x += acc1.x; acc0.y += acc1.y; acc0.z += acc1.z; acc0.w += acc1.w;
        #pragma unroll
        for (int m = 16; m < 64; m <<= 1) {
            acc0.x += __shfl_xor(acc0.x, m);
            acc0.y += __shfl_xor(acc0.y, m);
            acc0.z += __shfl_xor(acc0.z, m);
            acc0.w += __shfl_xor(acc0.w, m);
        }
        if (grp == 0) {
            float rsd = rs[node];
            float4 sk = ((const float4*)(h + (size_t)node * HDIM))[gl];
            acc0.x = acc0.x * rsd + sk.x;
            acc0.y = acc0.y * rsd + sk.y;
            acc0.z = acc0.z * rsd + sk.z;
            acc0.w = acc0.w * rsd + sk.w;
            *(float4*)&hbuf[wave][i][gl * 4] = acc0;
        }
    }

    // ---- phase 2: GEMM the wave's 8 rows (R=1: row ty, cols tx*8..+7) ----
    // (same-wave ds_write -> ds_read is in-order; no sync needed)
    int tx = lane & 7, ty = lane >> 3;
    float acc[8];
    #pragma unroll
    for (int i = 0; i < 8; i++) acc[i] = 0.f;
    #pragma unroll 4
    for (int k = 0; k < HDIM; k += 4) {
        float4 a4 = *(const float4*)&hbuf[wave][ty][k];
        #pragma unroll
        for (int kk = 0; kk < 4; kk++) {
            float4 b0 = *(const float4*)(w + (k + kk) * HDIM + tx * 8);
            float4 b1 = *(const float4*)(w + (k + kk) * HDIM + tx * 8 + 4);
            float av = (kk == 0) ? a4.x : (kk == 1) ? a4.y
                     : (kk == 2) ? a4.z : a4.w;
            acc[0] += av * b0.x; acc[1] += av * b0.y;
            acc[2] += av * b0.z; acc[3] += av * b0.w;
            acc[4] += av * b1.x; acc[5] += av * b1.y;
            acc[6] += av * b1.z; acc[7] += av * b1.w;
        }
    }
    int node2 = wbase + ty;
    float4 o0, o1;
    o0.x = fmaxf(acc[0], 0.f); o0.y = fmaxf(acc[1], 0.f);
    o0.z = fmaxf(acc[2], 0.f); o0.w = fmaxf(acc[3], 0.f);
    o1.x = fmaxf(acc[4], 0.f); o1.y = fmaxf(acc[5], 0.f);
    o1.z = fmaxf(acc[6], 0.f); o1.w = fmaxf(acc[7], 0.f);

    if (!LAST) {
        if (node2 < n) {
            *(float4*)(h + (size_t)node2 * HDIM + tx * 8) = o0;
            *(float4*)(h + (size_t)node2 * HDIM + tx * 8 + 4) = o1;
            float rsv = rs[node2];
            __half2 p0 = __floats2half2_rn(rsv * o0.x, rsv * o0.y);
            __half2 p1 = __floats2half2_rn(rsv * o0.z, rsv * o0.w);
            __half2 p2 = __floats2half2_rn(rsv * o1.x, rsv * o1.y);
            __half2 p3 = __floats2half2_rn(rsv * o1.z, rsv * o1.w);
            uint4 pk;
            pk.x = *(unsigned int*)&p0;
            pk.y = *(unsigned int*)&p1;
            pk.z = *(unsigned int*)&p2;
            pk.w = *(unsigned int*)&p3;
            *(uint4*)(h16out + (size_t)node2 * HDIM + tx * 8) = pk;
        }
    } else {
        // write relu rows back in place (lockstep: GEMM reads already done)
        *(float4*)&hbuf[wave][ty][tx * 8] = o0;
        *(float4*)&hbuf[wave][ty][tx * 8 + 4] = o1;
        // ---- phase 3: out[row tn] cols cg*4..+3 = hrow . Wout ----
        int tn = lane >> 3, cg = lane & 7;
        float4 s = make_float4(0.f, 0.f, 0.f, 0.f);
        #pragma unroll 8
        for (int k = 0; k < HDIM; k++) {
            float hv = hbuf[wave][tn][k];
            float4 wv = *(const float4*)&wo[k * OUTDIM + cg * 4];
            s.x += hv * wv.x; s.y += hv * wv.y;
            s.z += hv * wv.z; s.w += hv * wv.w;
        }
        int node3 = wbase + tn;
        if (node3 < n)
            *(float4*)(outp + (size_t)node3 * OUTDIM + cg * 4) = s;
    }
}

extern "C" void kernel_launch(void* const* d_in, const int* in_sizes, int n_in,
                              void* d_out, int out_size, void* d_ws, size_t ws_size,
                              hipStream_t stream) {
    const float* x    = (const float*)d_in[0];
    const int*   ei   = (const int*)d_in[1];
    const float* Win  = (const float*)d_in[2];
    const float* Wl   = (const float*)d_in[3];
    const float* Wout = (const float*)d_in[4];
    float* out = (float*)d_out;

    int n = in_sizes[0] / INDIM;   // 100000
    int e = in_sizes[1] / 2;       // 1600000
    const int* dst = ei;           // edge_index[0]
    const int* src = ei + e;       // edge_index[1]

    int nb = (n + BNODES - 1) / BNODES;   // 782 buckets

    // workspace: gcur | cnt | rs | binned | csr_pad | h | h16a | h16b
    char* w = (char*)d_ws;
    int* gcur = (int*)w;      w += 1024 * 4;
    int* cnt = (int*)w;       w += (size_t)n * 4;
    float* rs = (float*)w;    w += (size_t)n * 4;
    w = (char*)(((uintptr_t)w + 255) & ~(uintptr_t)255);
    int* binned = (int*)w;    w += (size_t)nb * BCAP * 4;          // 7.2 MB
    int* csr = (int*)w;       w += (size_t)nb * BNODES * CAP * 4;  // 25.6 MB
    float* h = (float*)w;     w += (size_t)n * HDIM * 4;           // 25.6 MB
    __half* h16a = (__half*)w; w += (size_t)n * HDIM * 2;          // 12.8 MB
    __half* h16b = (__half*)w; w += (size_t)n * HDIM * 2;          // 12.8 MB

    hipMemsetAsync(gcur, 0, 1024 * 4, stream);

    // two-phase padded-CSR build
    int ablocks = (e + EPB - 1) / EPB;    // 391
    bin_edges<<<ablocks, 256, 0, stream>>>(dst, src, gcur, binned, e, nb);
    build_csr<<<nb, 256, 0, stream>>>(gcur, binned, cnt, rs, csr, n);

    // h = x @ W_in  (+ rs-scaled fp16 shadow h16a)
    int g64 = (n + 63) / 64;   // 1563 blocks
    gemm_node<INDIM, HDIM, 64, 256, false, true><<<g64, 256, 0, stream>>>(
        x, Win, h, h16a, rs, n);

    // fused layers (64 nodes/block, 8 waves x 8 nodes)
    layer_fused2<0><<<g64, 512, 0, stream>>>(h16a, h, h16b, nullptr,
                                             Wl, nullptr, cnt, csr, rs, n);
    layer_fused2<1><<<g64, 512, 0, stream>>>(h16b, h, nullptr, out,
                                             Wl + (size_t)HDIM * HDIM, Wout,
                                             cnt, csr, rs, n);
}

// Round 15
// 192.057 us; speedup vs baseline: 1.1643x; 1.1643x over previous
//
#include <hip/hip_runtime.h>
#include <hip/hip_fp16.h>

#define HDIM 64
#define INDIM 128
#define OUTDIM 32
#define CAP 64        // padded-CSR capacity per node; deg ~ Poisson(16)
#define BNODES 128    // nodes per bucket (bucket = dst >> 7)
#define EPB 4096      // edges per block in pass A
#define BCAP 2304     // per-bucket edge capacity (mean 2046, +5.7 sigma)
#define SRCBITS 17    // src ids < 2^17 (n <= 131072)

__device__ __forceinline__ float2 h2f(unsigned int u) {
    return __half22float2(*(__half2*)&u);
}

// ---------------- pass A: bin edges by dst-bucket ----------------
__global__ __launch_bounds__(256) void bin_edges(const int* __restrict__ dst,
                                                 const int* __restrict__ src,
                                                 int* __restrict__ gcur,
                                                 int* __restrict__ binned,
                                                 int e, int nb) {
    __shared__ int hist[1024];
    __shared__ int base[1024];
    for (int i = threadIdx.x; i < nb; i += 256) hist[i] = 0;
    __syncthreads();

    int e0 = blockIdx.x * EPB + (int)threadIdx.x * 16;
    int d[16], s[16], p[16];
    bool vec_ok = ((e & 3) == 0);
    #pragma unroll
    for (int k = 0; k < 4; k++) {
        int i = e0 + 4 * k;
        if (vec_ok && i + 4 <= e) {
            int4 d4 = *(const int4*)(dst + i);
            int4 s4 = *(const int4*)(src + i);
            d[4*k+0] = d4.x; d[4*k+1] = d4.y; d[4*k+2] = d4.z; d[4*k+3] = d4.w;
            s[4*k+0] = s4.x; s[4*k+1] = s4.y; s[4*k+2] = s4.z; s[4*k+3] = s4.w;
        } else {
            #pragma unroll
            for (int j = 0; j < 4; j++) {
                int ii = i + j;
                if (ii < e) { d[4*k+j] = dst[ii]; s[4*k+j] = src[ii]; }
                else        { d[4*k+j] = -1;      s[4*k+j] = 0; }
            }
        }
    }
    #pragma unroll
    for (int k = 0; k < 16; k++)
        if (d[k] >= 0) p[k] = atomicAdd(&hist[d[k] >> 7], 1);
    __syncthreads();
    for (int b = threadIdx.x; b < nb; b += 256) {
        int h = hist[b];
        base[b] = h ? atomicAdd(&gcur[b], h) : 0;
    }
    __syncthreads();
    #pragma unroll
    for (int k = 0; k < 16; k++) {
        if (d[k] < 0) continue;
        int b = d[k] >> 7;
        int pos = base[b] + p[k];
        if (pos < BCAP)
            binned[(size_t)b * BCAP + pos] = ((d[k] & (BNODES - 1)) << SRCBITS) | s[k];
    }
}

// ---------------- pass B: per-bucket padded CSR built in LDS ----------------
__global__ __launch_bounds__(256) void build_csr(const int* __restrict__ gcur,
                                                 const int* __restrict__ binned,
                                                 int* __restrict__ cnt,
                                                 float* __restrict__ rs,
                                                 float* __restrict__ isr,
                                                 int* __restrict__ csr, int n) {
    __shared__ int lcsr[BNODES * CAP];   // 32 KiB
    __shared__ int lcnt[BNODES];
    if (threadIdx.x < BNODES) lcnt[threadIdx.x] = 0;
    __syncthreads();
    int b = blockIdx.x;
    int m = min(gcur[b], BCAP);
    const int* be = binned + (size_t)b * BCAP;
    for (int i = threadIdx.x; i < m; i += 256) {
        int v = be[i];
        int ld = v >> SRCBITS;
        int pos = atomicAdd(&lcnt[ld], 1);
        if (pos < CAP) lcsr[ld * CAP + pos] = v & ((1 << SRCBITS) - 1);
    }
    __syncthreads();
    int4* gout = (int4*)(csr + (size_t)b * (BNODES * CAP));
    const int4* lin = (const int4*)lcsr;
    #pragma unroll 2
    for (int i = threadIdx.x; i < BNODES * CAP / 4; i += 256) gout[i] = lin[i];
    int node = b * BNODES + (int)threadIdx.x;
    if (threadIdx.x < BNODES && node < n) {
        int c = lcnt[threadIdx.x];
        cnt[node] = c;
        float cf = (float)c + 1.0f;
        rs[node] = rsqrtf(cf);
        isr[node] = sqrtf(cf);   // 1/rs: recovers unscaled h from the shadow
    }
}

// ---------------- node GEMM -> fp16 shadow only: C16 = fp16(rs * op(A@W)) --
// A16: A is fp16 (uint4 = 8 halves per load). All intermediate node arrays
// are fp16 now; fp32 h/agg round-trips eliminated. BM=64/BLOCK=256 -> 1563
// blocks (~6/CU, better balance than 782x8-wave). No launch-bounds min-arg
// (R10: hipcc CUDA semantics -> VGPR cap -> spill).
template<int K, bool A16, bool RELU>
__global__ __launch_bounds__(256) void gemm_h16(const void* __restrict__ Av,
                                                const float* __restrict__ W,
                                                __half* __restrict__ C16,
                                                const float* __restrict__ rs, int n) {
    constexpr int N = HDIM, BM = 64, R = 2;
    __shared__ float w[K * N];
    for (int i = threadIdx.x; i < K * N; i += 256) w[i] = W[i];
    __syncthreads();
    int tx = (int)threadIdx.x & 7;        // 8 col-groups of 8
    int ty = (int)threadIdx.x >> 3;       // 32 row-groups
    int base = blockIdx.x * BM + ty * R;

    float acc[R][8];
    #pragma unroll
    for (int r = 0; r < R; r++)
        #pragma unroll
        for (int i = 0; i < 8; i++) acc[r][i] = 0.f;

    if (A16) {
        const __half* A = (const __half*)Av;
        const uint4* pa[R];
        #pragma unroll
        for (int r = 0; r < R; r++) {
            int row = base + r;
            row = row < n ? row : n - 1;
            pa[r] = (const uint4*)(A + (size_t)row * K);
        }
        #pragma unroll 2
        for (int c8 = 0; c8 < K / 8; c8++) {
            uint4 a8[R];
            #pragma unroll
            for (int r = 0; r < R; r++) a8[r] = pa[r][c8];
            float af[R][8];
            #pragma unroll
            for (int r = 0; r < R; r++) {
                float2 t0 = h2f(a8[r].x), t1 = h2f(a8[r].y);
                float2 t2 = h2f(a8[r].z), t3 = h2f(a8[r].w);
                af[r][0] = t0.x; af[r][1] = t0.y; af[r][2] = t1.x; af[r][3] = t1.y;
                af[r][4] = t2.x; af[r][5] = t2.y; af[r][6] = t3.x; af[r][7] = t3.y;
            }
            #pragma unroll
            for (int kk = 0; kk < 8; kk++) {
                float4 b0 = *(const float4*)(w + (c8 * 8 + kk) * N + tx * 8);
                float4 b1 = *(const float4*)(w + (c8 * 8 + kk) * N + tx * 8 + 4);
                #pragma unroll
                for (int r = 0; r < R; r++) {
                    float av = af[r][kk];
                    acc[r][0] += av * b0.x; acc[r][1] += av * b0.y;
                    acc[r][2] += av * b0.z; acc[r][3] += av * b0.w;
                    acc[r][4] += av * b1.x; acc[r][5] += av * b1.y;
                    acc[r][6] += av * b1.z; acc[r][7] += av * b1.w;
                }
            }
        }
    } else {
        const float* A = (const float*)Av;
        const float* pa[R];
        #pragma unroll
        for (int r = 0; r < R; r++) {
            int row = base + r;
            row = row < n ? row : n - 1;
            pa[r] = A + (size_t)row * K;
        }
        #pragma unroll 4
        for (int k = 0; k < K; k += 4) {
            float4 a4[R];
            #pragma unroll
            for (int r = 0; r < R; r++) a4[r] = *(const float4*)(pa[r] + k);
            #pragma unroll
            for (int kk = 0; kk < 4; kk++) {
                float4 b0 = *(const float4*)(w + (k + kk) * N + tx * 8);
                float4 b1 = *(const float4*)(w + (k + kk) * N + tx * 8 + 4);
                #pragma unroll
                for (int r = 0; r < R; r++) {
                    float av = (kk == 0) ? a4[r].x : (kk == 1) ? a4[r].y
                             : (kk == 2) ? a4[r].z : a4[r].w;
                    acc[r][0] += av * b0.x; acc[r][1] += av * b0.y;
                    acc[r][2] += av * b0.z; acc[r][3] += av * b0.w;
                    acc[r][4] += av * b1.x; acc[r][5] += av * b1.y;
                    acc[r][6] += av * b1.z; acc[r][7] += av * b1.w;
                }
            }
        }
    }

    #pragma unroll
    for (int r = 0; r < R; r++) {
        int node = base + r;
        if (node >= n) continue;
        float rsv = rs[node];
        float v0 = RELU ? fmaxf(acc[r][0], 0.f) : acc[r][0];
        float v1 = RELU ? fmaxf(acc[r][1], 0.f) : acc[r][1];
        float v2 = RELU ? fmaxf(acc[r][2], 0.f) : acc[r][2];
        float v3 = RELU ? fmaxf(acc[r][3], 0.f) : acc[r][3];
        float v4 = RELU ? fmaxf(acc[r][4], 0.f) : acc[r][4];
        float v5 = RELU ? fmaxf(acc[r][5], 0.f) : acc[r][5];
        float v6 = RELU ? fmaxf(acc[r][6], 0.f) : acc[r][6];
        float v7 = RELU ? fmaxf(acc[r][7], 0.f) : acc[r][7];
        __half2 p0 = __floats2half2_rn(rsv * v0, rsv * v1);
        __half2 p1 = __floats2half2_rn(rsv * v2, rsv * v3);
        __half2 p2 = __floats2half2_rn(rsv * v4, rsv * v5);
        __half2 p3 = __floats2half2_rn(rsv * v6, rsv * v7);
        uint4 pk;
        pk.x = *(unsigned int*)&p0;
        pk.y = *(unsigned int*)&p1;
        pk.z = *(unsigned int*)&p2;
        pk.w = *(unsigned int*)&p3;
        *(uint4*)(C16 + (size_t)node * HDIM + tx * 8) = pk;
    }
}

// ---------------- fused last layer: out = relu((agg) @ W1) @ Wout ----------
// fp16 A rows; relu rows staged in LDS hbuf (stride 68, <=2-way aliasing for
// the b32/broadcast patterns used); second multiply emits out directly.
__global__ __launch_bounds__(512) void gemm_last(const __half* __restrict__ A,
                                                 const float* __restrict__ W2,
                                                 const float* __restrict__ Wo,
                                                 float* __restrict__ outp, int n) {
    __shared__ float w[HDIM * HDIM];       // 16 KB
    __shared__ float wo[HDIM * OUTDIM];    // 8 KB
    __shared__ __align__(16) float hbuf[128][68];  // 34.8 KB
    for (int i = threadIdx.x; i < HDIM * HDIM; i += 512) w[i] = W2[i];
    for (int i = threadIdx.x; i < HDIM * OUTDIM; i += 512) wo[i] = Wo[i];
    __syncthreads();
    constexpr int R = 2;
    int tx = (int)threadIdx.x & 7;
    int ty = (int)threadIdx.x >> 3;       // 0..63
    int bn = blockIdx.x * 128;
    int base = bn + ty * R;

    const uint4* pa[R];
    #pragma unroll
    for (int r = 0; r < R; r++) {
        int row = base + r;
        row = row < n ? row : n - 1;
        pa[r] = (const uint4*)(A + (size_t)row * HDIM);
    }
    float acc[R][8];
    #pragma unroll
    for (int r = 0; r < R; r++)
        #pragma unroll
        for (int i = 0; i < 8; i++) acc[r][i] = 0.f;

    #pragma unroll 2
    for (int c8 = 0; c8 < HDIM / 8; c8++) {
        uint4 a8[R];
        #pragma unroll
        for (int r = 0; r < R; r++) a8[r] = pa[r][c8];
        float af[R][8];
        #pragma unroll
        for (int r = 0; r < R; r++) {
            float2 t0 = h2f(a8[r].x), t1 = h2f(a8[r].y);
            float2 t2 = h2f(a8[r].z), t3 = h2f(a8[r].w);
            af[r][0] = t0.x; af[r][1] = t0.y; af[r][2] = t1.x; af[r][3] = t1.y;
            af[r][4] = t2.x; af[r][5] = t2.y; af[r][6] = t3.x; af[r][7] = t3.y;
        }
        #pragma unroll
        for (int kk = 0; kk < 8; kk++) {
            float4 b0 = *(const float4*)(w + (c8 * 8 + kk) * HDIM + tx * 8);
            float4 b1 = *(const float4*)(w + (c8 * 8 + kk) * HDIM + tx * 8 + 4);
            #pragma unroll
            for (int r = 0; r < R; r++) {
                float av = af[r][kk];
                acc[r][0] += av * b0.x; acc[r][1] += av * b0.y;
                acc[r][2] += av * b0.z; acc[r][3] += av * b0.w;
                acc[r][4] += av * b1.x; acc[r][5] += av * b1.y;
                acc[r][6] += av * b1.z; acc[r][7] += av * b1.w;
            }
        }
    }
    #pragma unroll
    for (int r = 0; r < R; r++) {
        int lr = ty * R + r;
        float4 o0, o1;
        o0.x = fmaxf(acc[r][0], 0.f); o0.y = fmaxf(acc[r][1], 0.f);
        o0.z = fmaxf(acc[r][2], 0.f); o0.w = fmaxf(acc[r][3], 0.f);
        o1.x = fmaxf(acc[r][4], 0.f); o1.y = fmaxf(acc[r][5], 0.f);
        o1.z = fmaxf(acc[r][6], 0.f); o1.w = fmaxf(acc[r][7], 0.f);
        *(float4*)&hbuf[lr][tx * 8] = o0;
        *(float4*)&hbuf[lr][tx * 8 + 4] = o1;
    }
    __syncthreads();
    int tn = (int)threadIdx.x >> 2;
    int cg = (int)threadIdx.x & 3;
    int node = bn + tn;
    if (node >= n) return;
    float4 s0 = make_float4(0.f, 0.f, 0.f, 0.f);
    float4 s1 = make_float4(0.f, 0.f, 0.f, 0.f);
    #pragma unroll 4
    for (int k = 0; k < HDIM; k++) {
        float hv = hbuf[tn][k];
        float4 w0 = *(const float4*)(wo + k * OUTDIM + cg * 8);
        float4 w1 = *(const float4*)(wo + k * OUTDIM + cg * 8 + 4);
        s0.x += hv * w0.x; s0.y += hv * w0.y; s0.z += hv * w0.z; s0.w += hv * w0.w;
        s1.x += hv * w1.x; s1.y += hv * w1.y; s1.z += hv * w1.z; s1.w += hv * w1.w;
    }
    *(float4*)(outp + (size_t)node * OUTDIM + cg * 8) = s0;
    *(float4*)(outp + (size_t)node * OUTDIM + cg * 8 + 4) = s1;
}

// ---------------- agg16[d] = fp16(rs[d]*sum h16[s] + isr[d]*h16[d]) --------
// 4x16-lane groups, 4-deep unrolled edge loop: 16 independent 128B gathers
// in flight per wave (VGPR ~40, occupancy preserved). All fp16 in/out.
__global__ void aggregate(const __half* __restrict__ h16in,
                          __half* __restrict__ agg16,
                          const int* __restrict__ cnt, const int* __restrict__ csr,
                          const float* __restrict__ rs, const float* __restrict__ isr,
                          int n) {
    int wave = threadIdx.x >> 6;
    int lane = threadIdx.x & 63;
    int node = blockIdx.x * (blockDim.x >> 6) + wave;
    if (node >= n) return;
    int c = min(cnt[node], CAP);
    int grp = lane >> 4;
    int gl = lane & 15;
    int sl = 0;
    if (lane < c) sl = csr[node * CAP + lane];
    float4 acc0 = make_float4(0.f, 0.f, 0.f, 0.f);
    float4 acc1 = make_float4(0.f, 0.f, 0.f, 0.f);
    int trips = (c + 3) >> 2;
    int j = 0;
    for (; j + 4 <= trips; j += 4) {
        #pragma unroll
        for (int u = 0; u < 2; u++) {
            int ta = 4 * (j + 2 * u) + grp, tb = ta + 4;
            float wa = (ta < c) ? 1.f : 0.f;
            float wb = (tb < c) ? 1.f : 0.f;
            int ua = min(ta, c - 1), ub = min(tb, c - 1);
            int sa = __shfl(sl, ua), sb = __shfl(sl, ub);
            uint2 qa = ((const uint2*)(h16in + (size_t)sa * HDIM))[gl];
            uint2 qb = ((const uint2*)(h16in + (size_t)sb * HDIM))[gl];
            float2 fa0 = h2f(qa.x), fa1 = h2f(qa.y);
            float2 fb0 = h2f(qb.x), fb1 = h2f(qb.y);
            acc0.x += wa * fa0.x; acc0.y += wa * fa0.y;
            acc0.z += wa * fa1.x; acc0.w += wa * fa1.y;
            acc1.x += wb * fb0.x; acc1.y += wb * fb0.y;
            acc1.z += wb * fb1.x; acc1.w += wb * fb1.y;
        }
    }
    for (; j < trips; j++) {
        int t = 4 * j + grp;
        float wv = (t < c) ? 1.f : 0.f;
        int u = min(t, c - 1);
        int s = __shfl(sl, u);
        uint2 q = ((const uint2*)(h16in + (size_t)s * HDIM))[gl];
        float2 fa = h2f(q.x), fb = h2f(q.y);
        acc0.x += wv * fa.x; acc0.y += wv * fa.y;
        acc0.z += wv * fb.x; acc0.w += wv * fb.y;
    }
    acc0.x += acc1.x; acc0.y += acc1.y; acc0.z += acc1.z; acc0.w += acc1.w;
    #pragma unroll
    for (int m = 16; m < 64; m <<= 1) {
        acc0.x += __shfl_xor(acc0.x, m);
        acc0.y += __shfl_xor(acc0.y, m);
        acc0.z += __shfl_xor(acc0.z, m);
        acc0.w += __shfl_xor(acc0.w, m);
    }
    if (grp == 0) {
        float rsd = rs[node];
        float isrd = isr[node];
        uint2 sk2 = ((const uint2*)(h16in + (size_t)node * HDIM))[gl];
        float2 ska = h2f(sk2.x), skb = h2f(sk2.y);
        acc0.x = acc0.x * rsd + ska.x * isrd;
        acc0.y = acc0.y * rsd + ska.y * isrd;
        acc0.z = acc0.z * rsd + skb.x * isrd;
        acc0.w = acc0.w * rsd + skb.y * isrd;
        __half2 q0 = __floats2half2_rn(acc0.x, acc0.y);
        __half2 q1 = __floats2half2_rn(acc0.z, acc0.w);
        uint2 st;
        st.x = *(unsigned int*)&q0;
        st.y = *(unsigned int*)&q1;
        ((uint2*)(agg16 + (size_t)node * HDIM))[gl] = st;
    }
}

extern "C" void kernel_launch(void* const* d_in, const int* in_sizes, int n_in,
                              void* d_out, int out_size, void* d_ws, size_t ws_size,
                              hipStream_t stream) {
    const float* x    = (const float*)d_in[0];
    const int*   ei   = (const int*)d_in[1];
    const float* Win  = (const float*)d_in[2];
    const float* Wl   = (const float*)d_in[3];
    const float* Wout = (const float*)d_in[4];
    float* out = (float*)d_out;

    int n = in_sizes[0] / INDIM;   // 100000
    int e = in_sizes[1] / 2;       // 1600000
    const int* dst = ei;           // edge_index[0]
    const int* src = ei + e;       // edge_index[1]

    int nb = (n + BNODES - 1) / BNODES;   // 782 buckets

    // workspace: gcur | cnt | rs | isr | binned | csr | h16a | agg16a | h16b | agg16b
    char* w = (char*)d_ws;
    int* gcur = (int*)w;       w += 1024 * 4;
    int* cnt = (int*)w;        w += (size_t)n * 4;
    float* rs = (float*)w;     w += (size_t)n * 4;
    float* isr = (float*)w;    w += (size_t)n * 4;
    w = (char*)(((uintptr_t)w + 255) & ~(uintptr_t)255);
    int* binned = (int*)w;     w += (size_t)nb * BCAP * 4;          // 7.2 MB
    int* csr = (int*)w;        w += (size_t)nb * BNODES * CAP * 4;  // 25.6 MB
    __half* h16a = (__half*)w;   w += (size_t)n * HDIM * 2;         // 12.8 MB
    __half* agg16a = (__half*)w; w += (size_t)n * HDIM * 2;         // 12.8 MB
    __half* h16b = (__half*)w;   w += (size_t)n * HDIM * 2;         // 12.8 MB
    __half* agg16b = (__half*)w; w += (size_t)n * HDIM * 2;         // 12.8 MB

    hipMemsetAsync(gcur, 0, 1024 * 4, stream);

    // two-phase padded-CSR build
    int ablocks = (e + EPB - 1) / EPB;    // 391
    bin_edges<<<ablocks, 256, 0, stream>>>(dst, src, gcur, binned, e, nb);
    build_csr<<<nb, 256, 0, stream>>>(gcur, binned, cnt, rs, isr, csr, n);

    int g64 = (n + 63) / 64;      // 1563 blocks
    int g128 = (n + 127) / 128;   // 782 blocks

    // h16a = fp16(rs * (x @ W_in))
    gemm_h16<INDIM, false, false><<<g64, 256, 0, stream>>>(x, Win, h16a, rs, n);

    // layer 0
    aggregate<<<(n + 3) / 4, 256, 0, stream>>>(h16a, agg16a, cnt, csr, rs, isr, n);
    gemm_h16<HDIM, true, true><<<g64, 256, 0, stream>>>(agg16a, Wl, h16b, rs, n);

    // layer 1 + output
    aggregate<<<(n + 3) / 4, 256, 0, stream>>>(h16b, agg16b, cnt, csr, rs, isr, n);
    gemm_last<<<g128, 512, 0, stream>>>(agg16b, Wl + (size_t)HDIM * HDIM,
                                        Wout, out, n);
}